// Round 6
// baseline (78.954 us; speedup 1.0000x reference)
//
#include <hip/hip_runtime.h>

// WaveletMixing: out = x + IDWT3(scale(DWT3(x))) along N per (b,d) channel.
// x: (B=8, N=4096, D=768) f32.
// Block = 8 channels x 256 output samples (+halo), one LDS pool (31.1 KB,
// 5 blocks/CU). Interior tiles: refl-free 8-output vectorized tasks, all
// LDS traffic in b128, single iteration per phase. Residual x held in
// registers (8 early global loads). Edge tiles (nt=0,15): generic scalar.

namespace {

constexpr int NT  = 256;
constexpr int N0  = 4096;
constexpr int DCH = 768;
constexpr int G   = 8;              // channels per block
constexpr int T   = 256;            // output samples per block
constexpr int NTI = N0 / T;         // 16
constexpr int NDG = DCH / G;        // 96
constexpr int L1v = 2051, L2v = 1029, L3v = 518;  // pywt symmetric lengths

// LDS pool: per-channel segments (float offsets). SP = 972 (16B-aligned).
constexpr int SP   = 972;
constexpr int OX   = 0;    // x tile, origin n0-46, 352 real (356 alloc)
constexpr int OA1  = 356;  // a1 origin n0/2-20 (172 real); later r1 origin n0/2
constexpr int OD1  = 536;  // d1 origin n0/2-20  (180 alloc each)
constexpr int OA2  = 716;  // a2 origin n0/4-6 (82 real); later r2 origin n0/4
constexpr int OD2  = 804;  // d2 origin n0/4-6    (88 alloc each)
constexpr int OA3  = 892;  // a3 origin n0/8 (38 real; 40 alloc)
constexpr int OD3  = 932;  // d3 origin n0/8 (40 alloc)
constexpr int OREC = 716;  // final rec stage: 256 floats over dead a2|d2|a3|d3

// db4 analysis filters ascending (pywt); HI[k] = (-1)^(k+1)*LO[7-k].
__device__ constexpr float LO[8] = {
  -0.010597401784997278f,  0.032883011666982945f,  0.030841381835986965f,
  -0.18703481171888114f,  -0.02798376941698385f,   0.6308807679295904f,
   0.7148465705525415f,    0.23037781330885523f };
__device__ constexpr float HI[8] = {
  -0.23037781330885523f,   0.7148465705525415f,   -0.6308807679295904f,
  -0.02798376941698385f,   0.18703481171888114f,   0.030841381835986965f,
  -0.032883011666982945f, -0.010597401784997278f };
// Address-ascending copies: F[7-k].
__device__ constexpr float LOF[8] = {
   0.23037781330885523f,   0.7148465705525415f,    0.6308807679295904f,
  -0.02798376941698385f,  -0.18703481171888114f,   0.030841381835986965f,
   0.032883011666982945f, -0.010597401784997278f };
__device__ constexpr float HIF[8] = {
  -0.010597401784997278f, -0.032883011666982945f,  0.030841381835986965f,
   0.18703481171888114f,  -0.02798376941698385f,  -0.6308807679295904f,
   0.7148465705525415f,   -0.23037781330885523f };

__device__ __forceinline__ int refl(int g, int n) {
  g = (g < 0) ? (-g - 1) : g;
  return (g >= n) ? (2 * n - 1 - g) : g;
}

// ---------- interior (refl-free) 8-wide vectorized phases ----------

// 8 outputs per task: out[8v+t] = sum_k F[k]*in[16v+2t+K+k], t=0..7.
// Reads 6x b128 (24 floats), writes 2x b128 each for a and d.
template <int K>
__device__ __forceinline__ void analyze_v8(const float* __restrict__ in,
                                           float* __restrict__ oa,
                                           float* __restrict__ od,
                                           int ntask, int i2) {
  if (i2 < ntask) {
    const int v = i2;
    float r[24];
#pragma unroll
    for (int j = 0; j < 6; ++j) {
      const float4 t = *reinterpret_cast<const float4*>(in + 16 * v + 4 * j);
      r[4*j+0] = t.x; r[4*j+1] = t.y; r[4*j+2] = t.z; r[4*j+3] = t.w;
    }
    float a[8], h[8];
#pragma unroll
    for (int t = 0; t < 8; ++t) {
      float av = 0.f, hv = 0.f;
#pragma unroll
      for (int k = 0; k < 8; ++k) {
        av = fmaf(LOF[k], r[2*t + K + k], av);
        hv = fmaf(HIF[k], r[2*t + K + k], hv);
      }
      a[t] = av; h[t] = hv;
    }
    *reinterpret_cast<float4*>(oa + 8*v)     = make_float4(a[0],a[1],a[2],a[3]);
    *reinterpret_cast<float4*>(oa + 8*v + 4) = make_float4(a[4],a[5],a[6],a[7]);
    *reinterpret_cast<float4*>(od + 8*v)     = make_float4(h[0],h[1],h[2],h[3]);
    *reinterpret_cast<float4*>(od + 8*v + 4) = make_float4(h[4],h[5],h[6],h[7]);
  }
}

// Synthesis L3: 16 outputs per task. rec[2t]=sum LO[2m+1]ca[t+m]+HI[2m+1]cd[t+m],
// rec[2t+1] even taps; ca=a3, cd=d3 same origin. t = 8u..8u+7.
__device__ __forceinline__ void synth3_v8(const float* __restrict__ pa,
                                          const float* __restrict__ pd,
                                          float* __restrict__ o, float sa,
                                          float sd, int ntask, int i2) {
  if (i2 < ntask) {
    const int u = i2;
    float ra[12], rd[12];
#pragma unroll
    for (int j = 0; j < 3; ++j) {
      const float4 t0 = *reinterpret_cast<const float4*>(pa + 8*u + 4*j);
      const float4 t1 = *reinterpret_cast<const float4*>(pd + 8*u + 4*j);
      ra[4*j+0]=t0.x; ra[4*j+1]=t0.y; ra[4*j+2]=t0.z; ra[4*j+3]=t0.w;
      rd[4*j+0]=t1.x; rd[4*j+1]=t1.y; rd[4*j+2]=t1.z; rd[4*j+3]=t1.w;
    }
    float ov[16];
#pragma unroll
    for (int tt = 0; tt < 8; ++tt) {
      float e = 0.f, ed = 0.f, oe = 0.f, od_ = 0.f;
#pragma unroll
      for (int m = 0; m < 4; ++m) {
        e   = fmaf(LO[2*m+1], ra[tt+m], e);
        ed  = fmaf(HI[2*m+1], rd[tt+m], ed);
        oe  = fmaf(LO[2*m],   ra[tt+m], oe);
        od_ = fmaf(HI[2*m],   rd[tt+m], od_);
      }
      ov[2*tt]   = sa * e  + sd * ed;
      ov[2*tt+1] = sa * oe + sd * od_;
    }
#pragma unroll
    for (int j = 0; j < 4; ++j)
      *reinterpret_cast<float4*>(o + 16*u + 4*j) =
          make_float4(ov[4*j], ov[4*j+1], ov[4*j+2], ov[4*j+3]);
  }
}

// Synthesis L2: ca = r2 (origin n0/4, idx t'), cd = d2 (origin n0/4-6, idx
// t'+6). 16 outputs per task, t' = 8u..8u+7.
__device__ __forceinline__ void synth2_v8(const float* __restrict__ pa,
                                          const float* __restrict__ pd,
                                          float* __restrict__ o, float sd,
                                          int ntask, int i2) {
  if (i2 < ntask) {
    const int u = i2;
    float ra[12], rd[16];
#pragma unroll
    for (int j = 0; j < 3; ++j) {
      const float4 t0 = *reinterpret_cast<const float4*>(pa + 8*u + 4*j);
      ra[4*j+0]=t0.x; ra[4*j+1]=t0.y; ra[4*j+2]=t0.z; ra[4*j+3]=t0.w;
    }
#pragma unroll
    for (int j = 0; j < 4; ++j) {
      const float4 t1 = *reinterpret_cast<const float4*>(pd + 8*u + 4 + 4*j);
      rd[4*j+0]=t1.x; rd[4*j+1]=t1.y; rd[4*j+2]=t1.z; rd[4*j+3]=t1.w;
    }
    float ov[16];
#pragma unroll
    for (int tt = 0; tt < 8; ++tt) {
      float e = 0.f, ed = 0.f, oe = 0.f, od_ = 0.f;
#pragma unroll
      for (int m = 0; m < 4; ++m) {
        e   = fmaf(LO[2*m+1], ra[tt+m], e);
        ed  = fmaf(HI[2*m+1], rd[tt+2+m], ed);   // d2 idx t'+6+m
        oe  = fmaf(LO[2*m],   ra[tt+m], oe);
        od_ = fmaf(HI[2*m],   rd[tt+2+m], od_);
      }
      ov[2*tt]   = e  + sd * ed;
      ov[2*tt+1] = oe + sd * od_;
    }
#pragma unroll
    for (int j = 0; j < 4; ++j)
      *reinterpret_cast<float4*>(o + 16*u + 4*j) =
          make_float4(ov[4*j], ov[4*j+1], ov[4*j+2], ov[4*j+3]);
  }
}

// Final level: r1 (origin n0/2, idx t''), d1 (origin n0/2-20, idx t''+20).
// 8 outputs per task (u = i2, 32 tasks). No residual here (done at store).
__device__ __forceinline__ void final_v8(const float* __restrict__ pa,
                                         const float* __restrict__ pd,
                                         float* __restrict__ rec, float sd,
                                         int i2) {
  const int u = i2;
  float ra[8], rd[8];
#pragma unroll
  for (int j = 0; j < 2; ++j) {
    const float4 t0 = *reinterpret_cast<const float4*>(pa + 4*u + 4*j);
    const float4 t1 = *reinterpret_cast<const float4*>(pd + 4*u + 20 + 4*j);
    ra[4*j+0]=t0.x; ra[4*j+1]=t0.y; ra[4*j+2]=t0.z; ra[4*j+3]=t0.w;
    rd[4*j+0]=t1.x; rd[4*j+1]=t1.y; rd[4*j+2]=t1.z; rd[4*j+3]=t1.w;
  }
  float ov[8];
#pragma unroll
  for (int tt = 0; tt < 4; ++tt) {
    float e = 0.f, ed = 0.f, oe = 0.f, od_ = 0.f;
#pragma unroll
    for (int m = 0; m < 4; ++m) {
      e   = fmaf(LO[2*m+1], ra[tt+m], e);
      ed  = fmaf(HI[2*m+1], rd[tt+m], ed);
      oe  = fmaf(LO[2*m],   ra[tt+m], oe);
      od_ = fmaf(HI[2*m],   rd[tt+m], od_);
    }
    ov[2*tt]   = e  + sd * ed;
    ov[2*tt+1] = oe + sd * od_;
  }
  *reinterpret_cast<float4*>(rec + 8*u)     = make_float4(ov[0],ov[1],ov[2],ov[3]);
  *reinterpret_cast<float4*>(rec + 8*u + 4) = make_float4(ov[4],ov[5],ov[6],ov[7]);
}

// ---------- edge (generic, reflecting) scalar phases ----------

__device__ void analyze_g(const float* __restrict__ in, int Oin,
                          float* __restrict__ oa, float* __restrict__ od,
                          int cnt, int Oout, int lenout, int i2) {
  for (int p = i2; p < cnt; p += 32) {
    const int gp = refl(Oout + p, lenout);
    const int qb = 2 * gp - 6 - Oin;
    float alo = 0.f, ahi = 0.f;
#pragma unroll
    for (int k = 0; k < 8; ++k) {
      const float v = in[qb + k];
      alo = fmaf(LOF[k], v, alo);
      ahi = fmaf(HIF[k], v, ahi);
    }
    oa[p] = alo;
    od[p] = ahi;
  }
}

__device__ void synth_g(const float* __restrict__ ca,
                        const float* __restrict__ cd, int doff,
                        float* __restrict__ o, float sa, float sd, int npair,
                        int i2) {
  for (int t = i2; t < npair; t += 32) {
    float e = 0.f, ed = 0.f, oe = 0.f, od_ = 0.f;
#pragma unroll
    for (int m = 0; m < 4; ++m) {
      e   = fmaf(LO[2*m+1], ca[t+m], e);
      ed  = fmaf(HI[2*m+1], cd[t+doff+m], ed);
      oe  = fmaf(LO[2*m],   ca[t+m], oe);
      od_ = fmaf(HI[2*m],   cd[t+doff+m], od_);
    }
    o[2*t]   = sa * e  + sd * ed;
    o[2*t+1] = sa * oe + sd * od_;
  }
}

} // namespace

__global__ __launch_bounds__(NT) void wavemix_kernel(
    const float* __restrict__ x, const float* __restrict__ wap,
    const float* __restrict__ wdet, float* __restrict__ out) {
  __shared__ float pool[G * SP];   // 31104 B

  // Bijective XCD swizzle; consecutive wg = consecutive n-tiles of one
  // (b,dg) -> halo re-reads share an XCD's L2.
  const int cpx = gridDim.x >> 3;
  const int wg  = (blockIdx.x & 7) * cpx + (blockIdx.x >> 3);
  const int nt   = wg & (NTI - 1);
  const int rest = wg >> 4;              // / NTI
  const int dg   = rest % NDG;
  const int b    = rest / NDG;
  const int n0   = nt * T;
  const int d0   = dg * G;
  const int tid  = threadIdx.x;
  const bool edge = (nt == 0) || (nt == NTI - 1);

  // Store-phase roles, fixed at entry.
  const int cs = tid & 7;
  const int js = tid >> 3;               // 0..31

  // ---- early residual loads (interior): 8 regs, L1/L2-hit, latency hidden.
  float rx8[8];
  if (!edge) {
#pragma unroll
    for (int k = 0; k < 8; ++k)
      rx8[k] = x[((size_t)b * N0 + n0 + js + 32 * k) * DCH + d0 + cs];
  }

  // ---- load x tile [n0-46 .. n0+305] (coalesced float4 over 4 channels)
  {
    const int q  = tid & 1;
    const int pl = tid >> 1;
    for (int p = pl; p < 352; p += 128) {
      int g = n0 - 46 + p;
      if (edge) g = refl(g, N0);
      const float4 v = *reinterpret_cast<const float4*>(
          x + ((size_t)b * N0 + g) * DCH + d0 + 4 * q);
      float* dst = pool + (4 * q) * SP + OX + p;
      dst[0]      = v.x;
      dst[SP]     = v.y;
      dst[2 * SP] = v.z;
      dst[3 * SP] = v.w;
    }
  }

  const int c2 = tid >> 5;   // channel (compute phases)
  const int i2 = tid & 31;   // task slot
  float* P = pool + c2 * SP;
  const float wa = wap[d0 + c2];
  const float w2 = wdet[2 * DCH + d0 + c2];
  const float w1 = wdet[1 * DCH + d0 + c2];
  const float w0 = wdet[0 * DCH + d0 + c2];
  __syncthreads();

  if (!edge) {
    // K = 2*Oout - 6 - Oin: L1:0, L2:2, L3:0. (all single-iteration)
    analyze_v8<0>(P + OX,  P + OA1, P + OD1, 22, i2);  // a1/d1 0..175
    __syncthreads();
    analyze_v8<2>(P + OA1, P + OA2, P + OD2, 11, i2);  // a2/d2 0..87
    __syncthreads();
    analyze_v8<0>(P + OA2, P + OA3, P + OD3,  5, i2);  // a3/d3 0..39
    __syncthreads();
    synth3_v8(P + OA3, P + OD3, P + OA2, wa, w2, 5, i2);  // r2 0..79
    __syncthreads();
    synth2_v8(P + OA2, P + OD2, P + OA1, w1, 9, i2);      // r1 0..143
    __syncthreads();
    final_v8(P + OA1, P + OD1, P + OREC, w0, i2);         // rec 0..255
  } else {
    analyze_g(P + OX,  n0 - 46,      P + OA1, P + OD1, 172, n0 / 2 - 20, L1v, i2);
    __syncthreads();
    analyze_g(P + OA1, n0 / 2 - 20,  P + OA2, P + OD2,  82, n0 / 4 - 6,  L2v, i2);
    __syncthreads();
    analyze_g(P + OA2, n0 / 4 - 6,   P + OA3, P + OD3,  38, n0 / 8,      L3v, i2);
    __syncthreads();
    synth_g(P + OA3, P + OD3, 0, P + OA2, wa,  w2, 35, i2);  // r2 0..69
    __syncthreads();
    synth_g(P + OA2, P + OD2, 6, P + OA1, 1.f, w1, 66, i2);  // r1 0..131
    __syncthreads();
    for (int t = i2; t < 128; t += 32) {                     // final + residual
      const float* pa = P + OA1;
      const float* pd = P + OD1;
      float e = 0.f, ed = 0.f, oe = 0.f, od_ = 0.f;
#pragma unroll
      for (int m = 0; m < 4; ++m) {
        e   = fmaf(LO[2*m+1], pa[t+m], e);
        ed  = fmaf(HI[2*m+1], pd[t+20+m], ed);
        oe  = fmaf(LO[2*m],   pa[t+m], oe);
        od_ = fmaf(HI[2*m],   pd[t+20+m], od_);
      }
      (P + OREC)[2*t]   = e  + w0 * ed  + (P + OX)[2*t + 46];
      (P + OREC)[2*t+1] = oe + w0 * od_ + (P + OX)[2*t + 47];
    }
  }
  __syncthreads();

  // ---- coalesced store (+ register residual for interior)
  {
    const float* R = pool + cs * SP + OREC;
    float* orow = out + ((size_t)b * N0 + n0) * DCH + d0 + cs;
    if (!edge) {
#pragma unroll
      for (int k = 0; k < 8; ++k)
        orow[(size_t)(js + 32 * k) * DCH] = R[js + 32 * k] + rx8[k];
    } else {
      for (int pos = js; pos < T; pos += 32)
        orow[(size_t)pos * DCH] = R[pos];
    }
  }
}

extern "C" void kernel_launch(void* const* d_in, const int* in_sizes, int n_in,
                              void* d_out, int out_size, void* d_ws, size_t ws_size,
                              hipStream_t stream) {
  const float* x  = (const float*)d_in[0];
  const float* wa = (const float*)d_in[1];
  const float* wd = (const float*)d_in[2];
  float* out      = (float*)d_out;

  const int B    = in_sizes[0] / (N0 * DCH);   // 8
  const int grid = B * NDG * NTI;              // 12288, multiple of 8
  wavemix_kernel<<<grid, NT, 0, stream>>>(x, wa, wd, out);
}

// Round 7
// 61.788 us; speedup vs baseline: 1.2778x; 1.2778x over previous
//
#include <hip/hip_runtime.h>

// WaveletMixing: out = x + IDWT3(scale(DWT3(x))) along N per (b,d) channel.
// x: (B=8, N=4096, D=768) f32.
// Interior (n in [256,3840)): register-streaming dataflow pipeline.
//   thread = (channel d, segment s); lane = channel -> perfectly coalesced.
//   Per macro-step k: consume x[xs+8k..+7] (xs = n0-48), produce 4 a1/d1,
//   2 a2/d2, 1 a3/d3, 2 r2, 4 r1, 8 out (out batch = [n0-90+8k .. +7]).
//   All state in ~116 registers with static indices (2-step supersteps,
//   tail->head carry copies). No LDS, no barriers, no cross-lane.
// Edge tiles (nt=0,15): round-5 generic LDS path (proven), same dispatch,
//   interior blocks first so the long pole starts immediately.

namespace {

constexpr int NT  = 256;
constexpr int N0  = 4096;
constexpr int DCH = 768;
constexpr int T   = 256;
constexpr int G   = 8;               // edge path: channels per block
constexpr int NDG = DCH / G;         // 96
constexpr int L1v = 2051, L2v = 1029, L3v = 518;

constexpr int NINT = 8 * 14 * 3;     // 336 interior blocks (b x seg x 256-ch grp)

// Edge LDS pool (round-5 layout, proven)
constexpr int SP = 972;
constexpr int OX = 0, OA1 = 356, OD1 = 536, OA2 = 716, OD2 = 804,
              OA3 = 892, OD3 = 932, OREC = 716;

// db4 analysis filters ascending (pywt); HI[k] = (-1)^(k+1)*LO[7-k].
__device__ constexpr float LO[8] = {
  -0.010597401784997278f,  0.032883011666982945f,  0.030841381835986965f,
  -0.18703481171888114f,  -0.02798376941698385f,   0.6308807679295904f,
   0.7148465705525415f,    0.23037781330885523f };
__device__ constexpr float HI[8] = {
  -0.23037781330885523f,   0.7148465705525415f,   -0.6308807679295904f,
  -0.02798376941698385f,   0.18703481171888114f,   0.030841381835986965f,
  -0.032883011666982945f, -0.010597401784997278f };
// Address-ascending copies: F[7-k].
__device__ constexpr float LOF[8] = {
   0.23037781330885523f,   0.7148465705525415f,    0.6308807679295904f,
  -0.02798376941698385f,  -0.18703481171888114f,   0.030841381835986965f,
   0.032883011666982945f, -0.010597401784997278f };
__device__ constexpr float HIF[8] = {
  -0.010597401784997278f, -0.032883011666982945f,  0.030841381835986965f,
   0.18703481171888114f,  -0.02798376941698385f,  -0.6308807679295904f,
   0.7148465705525415f,   -0.23037781330885523f };

__device__ __forceinline__ int refl(int g, int n) {
  g = (g < 0) ? (-g - 1) : g;
  return (g >= n) ? (2 * n - 1 - g) : g;
}

// ---------------- streaming interior ----------------
// Array origins (abs coeff index of element 0, k0 = superstep's first step):
//  xa:  n0 + 8k0 - 54        a1a: n0/2 + 4k0 - 30   d1a: n0/2 + 4k0 - 45
//  a2a: n0/4 + 2k0 - 18      d2a: n0/4 + 2k0 - 21
//  a3a/d3a: n0/8 + k0 - 9    r2a: n0/4 + 2k0 - 21   r1a: n0/2 + 4k0 - 45
struct Streams {
  float xa[22];
  float a1a[14], d1a[29];
  float a2a[10], d2a[13];
  float a3a[5],  d3a[5];
  float r2a[7],  r1a[11];
};

// SMODE: 0 = no stores, 1 = HEAD (store u=1, tau>=1), 2 = FULL, 3 = TAIL
// (store u=0 all + u=1 tau=0). bk8 = 8*k0.
template <int SMODE>
__device__ __forceinline__ void superstep(Streams& S,
                                          const float* __restrict__ xrow,
                                          float* __restrict__ orow, int bk8,
                                          float wa, float w0, float w1,
                                          float w2) {
  // 16 independent x loads for this superstep (abs offsets bk8-48 .. bk8-33)
#pragma unroll
  for (int i = 0; i < 16; ++i)
    S.xa[6 + i] = xrow[(long)(bk8 - 48 + i) * DCH];

#pragma unroll
  for (int u = 0; u < 2; ++u) {
    // L1 analysis: 4 new a1/d1
#pragma unroll
    for (int j = 0; j < 4; ++j) {
      float slo = 0.f, shi = 0.f;
#pragma unroll
      for (int k = 0; k < 8; ++k) {
        const float v = S.xa[8 * u + 2 * j + k];
        slo = fmaf(LOF[k], v, slo);
        shi = fmaf(HIF[k], v, shi);
      }
      S.a1a[6 + 4 * u + j]  = slo;
      S.d1a[21 + 4 * u + j] = w0 * shi;
    }
    // L2 analysis: 2 new a2/d2
#pragma unroll
    for (int i = 0; i < 2; ++i) {
      float slo = 0.f, shi = 0.f;
#pragma unroll
      for (int k = 0; k < 8; ++k) {
        const float v = S.a1a[4 * u + 2 * i + k];
        slo = fmaf(LOF[k], v, slo);
        shi = fmaf(HIF[k], v, shi);
      }
      S.a2a[6 + 2 * u + i] = slo;
      S.d2a[9 + 2 * u + i] = w1 * shi;
    }
    // L3 analysis: 1 new a3/d3 (weights folded at production)
    {
      float slo = 0.f, shi = 0.f;
#pragma unroll
      for (int k = 0; k < 8; ++k) {
        const float v = S.a2a[2 * u + k];
        slo = fmaf(LOF[k], v, slo);
        shi = fmaf(HIF[k], v, shi);
      }
      S.a3a[3 + u] = wa * slo;
      S.d3a[3 + u] = w2 * shi;
    }
    // synth L3: 2 new r2 (even uses odd taps, odd uses even taps)
    {
      float e = 0.f, o = 0.f;
#pragma unroll
      for (int m = 0; m < 4; ++m) {
        e = fmaf(LO[2 * m + 1], S.a3a[u + m], e);
        e = fmaf(HI[2 * m + 1], S.d3a[u + m], e);
        o = fmaf(LO[2 * m],     S.a3a[u + m], o);
        o = fmaf(HI[2 * m],     S.d3a[u + m], o);
      }
      S.r2a[3 + 2 * u]     = e;
      S.r2a[3 + 2 * u + 1] = o;
    }
    // synth L2: 4 new r1
#pragma unroll
    for (int h = 0; h < 2; ++h) {
      float e = 0.f, o = 0.f;
#pragma unroll
      for (int m = 0; m < 4; ++m) {
        e = fmaf(LO[2 * m + 1], S.r2a[2 * u + h + m], e);
        e = fmaf(HI[2 * m + 1], S.d2a[2 * u + h + m], e);
        o = fmaf(LO[2 * m],     S.r2a[2 * u + h + m], o);
        o = fmaf(HI[2 * m],     S.d2a[2 * u + h + m], o);
      }
      S.r1a[3 + 4 * u + 2 * h]     = e;
      S.r1a[3 + 4 * u + 2 * h + 1] = o;
    }
    // synth L1 + residual + store (batch n = n0 + bk8 + 8u - 90 + {0..7})
    if (SMODE != 0) {
#pragma unroll
      for (int tau = 0; tau < 4; ++tau) {
        bool doSt;
        if (SMODE == 2)      doSt = true;
        else if (SMODE == 1) doSt = (u == 1) && (tau >= 1);
        else                 doSt = (u == 0) || (tau == 0);
        if (doSt) {
          float e = 0.f, o = 0.f;
#pragma unroll
          for (int m = 0; m < 4; ++m) {
            e = fmaf(LO[2 * m + 1], S.r1a[4 * u + tau + m], e);
            e = fmaf(HI[2 * m + 1], S.d1a[4 * u + tau + m], e);
            o = fmaf(LO[2 * m],     S.r1a[4 * u + tau + m], o);
            o = fmaf(HI[2 * m],     S.d1a[4 * u + tau + m], o);
          }
          const long ofs = bk8 + 8 * u - 90 + 2 * tau;
          orow[ofs * DCH]       = e + xrow[ofs * DCH];        // residual: L2 hit
          orow[(ofs + 1) * DCH] = o + xrow[(ofs + 1) * DCH];
        }
      }
    }
  }
  // carries: tail -> head (static renaming copies)
#pragma unroll
  for (int i = 0; i < 6; ++i)  S.xa[i]  = S.xa[i + 16];
#pragma unroll
  for (int i = 0; i < 6; ++i)  S.a1a[i] = S.a1a[i + 8];
#pragma unroll
  for (int i = 0; i < 21; ++i) S.d1a[i] = S.d1a[i + 8];
#pragma unroll
  for (int i = 0; i < 6; ++i)  S.a2a[i] = S.a2a[i + 4];
#pragma unroll
  for (int i = 0; i < 9; ++i)  S.d2a[i] = S.d2a[i + 4];
#pragma unroll
  for (int i = 0; i < 3; ++i) { S.a3a[i] = S.a3a[i + 2]; S.d3a[i] = S.d3a[i + 2]; }
#pragma unroll
  for (int i = 0; i < 3; ++i)  S.r2a[i] = S.r2a[i + 4];
#pragma unroll
  for (int i = 0; i < 3; ++i)  S.r1a[i] = S.r1a[i + 8];
}

// ---------------- edge (generic, reflecting) scalar phases ----------------

__device__ void analyze_g(const float* __restrict__ in, int Oin,
                          float* __restrict__ oa, float* __restrict__ od,
                          int cnt, int Oout, int lenout, int i2) {
  for (int p = i2; p < cnt; p += 32) {
    const int gp = refl(Oout + p, lenout);
    const int qb = 2 * gp - 6 - Oin;
    float alo = 0.f, ahi = 0.f;
#pragma unroll
    for (int k = 0; k < 8; ++k) {
      const float v = in[qb + k];
      alo = fmaf(LOF[k], v, alo);
      ahi = fmaf(HIF[k], v, ahi);
    }
    oa[p] = alo;
    od[p] = ahi;
  }
}

__device__ void synth_g(const float* __restrict__ ca,
                        const float* __restrict__ cd, int doff,
                        float* __restrict__ o, float sa, float sd, int npair,
                        int i2) {
  for (int t = i2; t < npair; t += 32) {
    float e = 0.f, ed = 0.f, oe = 0.f, od_ = 0.f;
#pragma unroll
    for (int m = 0; m < 4; ++m) {
      e   = fmaf(LO[2 * m + 1], ca[t + m], e);
      ed  = fmaf(HI[2 * m + 1], cd[t + doff + m], ed);
      oe  = fmaf(LO[2 * m],     ca[t + m], oe);
      od_ = fmaf(HI[2 * m],     cd[t + doff + m], od_);
    }
    o[2 * t]     = sa * e  + sd * ed;
    o[2 * t + 1] = sa * oe + sd * od_;
  }
}

} // namespace

__global__ __launch_bounds__(NT) void wavemix_kernel(
    const float* __restrict__ x, const float* __restrict__ wap,
    const float* __restrict__ wdet, float* __restrict__ out) {
  __shared__ float pool[G * SP];   // 31104 B (edge path only)
  const int blk = blockIdx.x;
  const int tid = threadIdx.x;

  if (blk < NINT) {
    // -------- register-streaming interior --------
    const int wgroup = blk % 3;
    const int rest   = blk / 3;
    const int s      = 1 + rest % 14;
    const int b      = rest / 14;
    const int n0     = s * T;
    const int d      = wgroup * 256 + tid;

    const float* __restrict__ xrow = x   + ((size_t)b * N0 + n0) * DCH + d;
    float* __restrict__       orow = out + ((size_t)b * N0 + n0) * DCH + d;
    const float wa = wap[d];
    const float w0 = wdet[d];
    const float w1 = wdet[DCH + d];
    const float w2 = wdet[2 * DCH + d];

    Streams S = {};
    int bk8 = 0;
    // warm-up: k = 0..9
#pragma unroll 1
    for (int m = 0; m < 5; ++m) {
      superstep<0>(S, xrow, orow, bk8, wa, w0, w1, w2);
      bk8 += 16;
    }
    // k = 10,11: first stores (n0..n0+5)
    superstep<1>(S, xrow, orow, bk8, wa, w0, w1, w2);
    bk8 += 16;
    // k = 12..41: full batches (n0+6 .. n0+245)
#pragma unroll 1
    for (int m = 0; m < 15; ++m) {
      superstep<2>(S, xrow, orow, bk8, wa, w0, w1, w2);
      bk8 += 16;
    }
    // k = 42,43: tail (n0+246 .. n0+255)
    superstep<3>(S, xrow, orow, bk8, wa, w0, w1, w2);
  } else {
    // -------- edge tiles (nt = 0 or 15), round-5 generic path --------
    const int e    = blk - NINT;
    const int nt   = (e & 1) ? 15 : 0;
    const int rest = e >> 1;
    const int dg   = rest % NDG;
    const int b    = rest / NDG;
    const int n0   = nt * T;
    const int d0   = dg * G;

    const size_t base = (size_t)b * N0 * DCH + d0;

    // load x tile [n0-46 .. n0+305] (reflected), coalesced float4
    {
      const int q  = tid & 1;
      const int pl = tid >> 1;
      for (int p = pl; p < 352; p += 128) {
        const int g = refl(n0 - 46 + p, N0);
        const float4 v = *reinterpret_cast<const float4*>(
            x + ((size_t)b * N0 + g) * DCH + d0 + 4 * q);
        float* dst = pool + (4 * q) * SP + OX + p;
        dst[0]      = v.x;
        dst[SP]     = v.y;
        dst[2 * SP] = v.z;
        dst[3 * SP] = v.w;
      }
    }

    const int c2 = tid >> 5;
    const int i2 = tid & 31;
    float* P = pool + c2 * SP;
    const float wa = wap[d0 + c2];
    const float w2 = wdet[2 * DCH + d0 + c2];
    const float w1 = wdet[1 * DCH + d0 + c2];
    const float w0 = wdet[0 * DCH + d0 + c2];
    __syncthreads();

    analyze_g(P + OX,  n0 - 46,     P + OA1, P + OD1, 172, n0 / 2 - 20, L1v, i2);
    __syncthreads();
    analyze_g(P + OA1, n0 / 2 - 20, P + OA2, P + OD2,  82, n0 / 4 - 6,  L2v, i2);
    __syncthreads();
    analyze_g(P + OA2, n0 / 4 - 6,  P + OA3, P + OD3,  38, n0 / 8,      L3v, i2);
    __syncthreads();
    synth_g(P + OA3, P + OD3, 0, P + OA2, wa,  w2, 35, i2);  // r2 0..69
    __syncthreads();
    synth_g(P + OA2, P + OD2, 6, P + OA1, 1.f, w1, 66, i2);  // r1 0..131
    __syncthreads();
    for (int t = i2; t < 128; t += 32) {                     // final + residual
      const float* pa = P + OA1;
      const float* pd = P + OD1;
      float e2 = 0.f, ed = 0.f, oe = 0.f, od_ = 0.f;
#pragma unroll
      for (int m = 0; m < 4; ++m) {
        e2  = fmaf(LO[2 * m + 1], pa[t + m], e2);
        ed  = fmaf(HI[2 * m + 1], pd[t + 20 + m], ed);
        oe  = fmaf(LO[2 * m],     pa[t + m], oe);
        od_ = fmaf(HI[2 * m],     pd[t + 20 + m], od_);
      }
      (P + OREC)[2 * t]     = e2 + w0 * ed  + (P + OX)[2 * t + 46];
      (P + OREC)[2 * t + 1] = oe + w0 * od_ + (P + OX)[2 * t + 47];
    }
    __syncthreads();

    // coalesced store
    {
      const int c = tid & 7;
      const int j = tid >> 3;
      const float* R = pool + c * SP + OREC;
      float* orow = out + ((size_t)b * N0 + n0) * DCH + d0 + c;
      for (int pos = j; pos < T; pos += 32)
        orow[(size_t)pos * DCH] = R[pos];
    }
  }
}

extern "C" void kernel_launch(void* const* d_in, const int* in_sizes, int n_in,
                              void* d_out, int out_size, void* d_ws, size_t ws_size,
                              hipStream_t stream) {
  const float* x  = (const float*)d_in[0];
  const float* wa = (const float*)d_in[1];
  const float* wd = (const float*)d_in[2];
  float* out      = (float*)d_out;

  const int grid = NINT + 8 * NDG * 2;   // 336 interior + 1536 edge = 1872
  wavemix_kernel<<<grid, NT, 0, stream>>>(x, wa, wd, out);
}